// Round 10
// baseline (3030.489 us; speedup 1.0000x reference)
//
#include <hip/hip_runtime.h>
#include <cstdint>

// Problem constants
#define B_   64
#define Z_   512
#define U_   2048
#define T_   32
#define DIN_ 90
#define G4_  8192      // 4*U
#define STLD 12288     // setup GEMM output row stride: h at +l*4096, c at +l*4096+2048

using bf16x8 = __attribute__((ext_vector_type(8))) short;   // 8 bf16 = 4 VGPRs
using f32x4  = __attribute__((ext_vector_type(4))) float;

#define MFMA(a, b, c) __builtin_amdgcn_mfma_f32_16x16x32_bf16((a), (b), (c), 0, 0, 0)

__device__ __forceinline__ unsigned short f2bf(float f) {
    unsigned int u = __float_as_uint(f);
    unsigned int r = (u + 0x7FFFu + ((u >> 16) & 1u)) >> 16;   // RNE
    return (unsigned short)r;
}
__device__ __forceinline__ float sigf(float x) { return 1.f / (1.f + expf(-x)); }

// async global->LDS, 16 B per lane; LDS dest is wave-uniform base + lane*16
__device__ __forceinline__ void gld16(const void* g, void* l) {
    __builtin_amdgcn_global_load_lds(
        (const __attribute__((address_space(1))) unsigned int*)g,
        (__attribute__((address_space(3))) unsigned int*)l, 16, 0, 0);
}

// ---------------- one-time weight prep ----------------

// Plain transpose: Wt[n*K + k] = bf16(W[(row_off+k)*N + n])
__global__ __launch_bounds__(256) void transpose_cvt(const float* __restrict__ W,
                                                     unsigned short* __restrict__ Wt,
                                                     int K, int N, int row_off)
{
    __shared__ float tile[32][33];
    const int nb = blockIdx.x * 32, kb = blockIdx.y * 32;
    const int tx = threadIdx.x & 31, ty = threadIdx.x >> 5;   // 32 x 8
    #pragma unroll
    for (int i = 0; i < 4; ++i)
        tile[ty + i * 8][tx] = W[(size_t)(row_off + kb + ty + i * 8) * N + nb + tx];
    __syncthreads();
    #pragma unroll
    for (int i = 0; i < 4; ++i)
        Wt[(size_t)(nb + ty + i * 8) * K + kb + tx] = f2bf(tile[tx][ty + i * 8]);
}

// Packed transpose: original col n = g*2048+u -> packed row (u>>3)*32 + g*8 + (u&7).
// Unit-tile block bx then owns packed rows [bx*32, bx*32+32).
__global__ __launch_bounds__(256) void transpose_cvt_packed(const float* __restrict__ W,
                                                            unsigned short* __restrict__ Wt)
{
    __shared__ float tile[32][33];
    const int nb = blockIdx.x * 32, kb = blockIdx.y * 32;   // N=8192, K=2048
    const int tx = threadIdx.x & 31, ty = threadIdx.x >> 5;
    #pragma unroll
    for (int i = 0; i < 4; ++i)
        tile[ty + i * 8][tx] = W[(size_t)(kb + ty + i * 8) * G4_ + nb + tx];
    __syncthreads();
    #pragma unroll
    for (int i = 0; i < 4; ++i) {
        int n = nb + ty + i * 8;
        int g = n >> 11, u = n & 2047;
        int prow = ((u >> 3) << 5) + (g << 3) + (u & 7);
        Wt[(size_t)prow * U_ + kb + tx] = f2bf(tile[tx][ty + i * 8]);
    }
}

// w_outT[d][k] = bf16(w_out[k*90+d]) for d<90, else 0   (96 x 2048)
__global__ __launch_bounds__(256) void wout_cvt(const float* __restrict__ w_out,
                                                unsigned short* __restrict__ w_outT)
{
    int i = blockIdx.x * 256 + threadIdx.x;        // 96*2048
    int d = i >> 11, k = i & 2047;
    w_outT[i] = (d < DIN_) ? f2bf(w_out[(size_t)k * DIN_ + d]) : (unsigned short)0;
}

__global__ __launch_bounds__(256) void cvt_z(const float* __restrict__ z,
                                             unsigned short* __restrict__ zb)
{
    int i = blockIdx.x * 256 + threadIdx.x;        // 64*512
    zb[i] = f2bf(z[i]);
}

// initial h (bf16) and c (fp32) from the setup GEMM output st
__global__ __launch_bounds__(256) void hcinit(const float* __restrict__ st,
                                              unsigned short* __restrict__ h0,
                                              unsigned short* __restrict__ h1,
                                              unsigned short* __restrict__ h2s0,
                                              float* __restrict__ c0,
                                              float* __restrict__ c1,
                                              float* __restrict__ c2)
{
    int idx = blockIdx.x * 256 + threadIdx.x;      // 3*64*2048
    int u = idx & 2047, b = (idx >> 11) & 63, ly = idx >> 17;
    float hv = st[(size_t)b * STLD + ly * 4096 + u];
    float cv = st[(size_t)b * STLD + ly * 4096 + 2048 + u];
    unsigned short* h = (ly == 0) ? h0 : (ly == 1) ? h1 : h2s0;
    float* c = (ly == 0) ? c0 : (ly == 1) ? c1 : c2;
    h[(size_t)b * 2048 + u] = f2bf(hv);
    c[(size_t)b * 2048 + u] = cv;
}

// ---------------- setup GEMMs (K=512): out[64 x N] = A @ Wt^T + bias ----------------
__global__ __launch_bounds__(256) void gemm_plain(const unsigned short* __restrict__ A, int K,
                                                  const unsigned short* __restrict__ Wt,
                                                  const float* __restrict__ bias,
                                                  float* __restrict__ out, int ldo)
{
    const int t = threadIdx.x, wv = t >> 6, l = t & 63;
    const int wm = (wv >> 1) * 32, n0 = blockIdx.x * 64 + (wv & 1) * 32;
    const int lr = l & 15, lk = (l >> 4) * 8;
    f32x4 acc[2][2] = {};
    for (int kt = 0; kt < K; kt += 32) {
        bf16x8 a0 = *(const bf16x8*)(A + (size_t)(wm + lr) * K + kt + lk);
        bf16x8 a1 = *(const bf16x8*)(A + (size_t)(wm + 16 + lr) * K + kt + lk);
        bf16x8 w0 = *(const bf16x8*)(Wt + (size_t)(n0 + lr) * K + kt + lk);
        bf16x8 w1 = *(const bf16x8*)(Wt + (size_t)(n0 + 16 + lr) * K + kt + lk);
        acc[0][0] = MFMA(a0, w0, acc[0][0]);
        acc[0][1] = MFMA(a0, w1, acc[0][1]);
        acc[1][0] = MFMA(a1, w0, acc[1][0]);
        acc[1][1] = MFMA(a1, w1, acc[1][1]);
    }
    #pragma unroll
    for (int mi = 0; mi < 2; ++mi)
        #pragma unroll
        for (int ni = 0; ni < 2; ++ni)
            #pragma unroll
            for (int r = 0; r < 4; ++r) {
                int row = wm + mi * 16 + (l >> 4) * 4 + r;
                int col = n0 + ni * 16 + lr;
                out[(size_t)row * ldo + col] = acc[mi][ni][r] + bias[col];
            }
}

// ---------------- core staged K=2048 GEMM phase + mode-specific epilogue ----------------
// Block 256 = 4 waves (rq=wv&1 row-half, ch=wv>>1 col-half), tile 32 rows x 32 packed
// cols, KT=128, 3 LDS stages, counted vmcnt(4). T2 XOR swizzle via pre-swizzled source.
// MODE 0: gate with xk0base (layer 0)     -> cst, hNew
// MODE 1: write S tile to zg (nontemporal)
// MODE 2: S += zg + bias -> gate          -> cst, hNew
template<int MODE>
__device__ __forceinline__ void lstm_phase(
    const unsigned short* __restrict__ A,      // [64][2048] activation rows
    const unsigned short* __restrict__ W,      // packed weights [8192][2048]
    const float* __restrict__ xk0base,         // MODE 0: [64][8192]
    const float* __restrict__ bias,            // MODE 2: [8192]
    float* __restrict__ zg,                    // MODE 1 (write) / MODE 2 (read): [64][8192]
    float* __restrict__ cst,                   // [64][2048]
    unsigned short* __restrict__ hNew)         // [64][2048]
{
    __shared__ char  stg[3 * 16384];           // 3 stages x (A 8KB | W 8KB)
    __shared__ float sg[32][33];
    const int t = threadIdx.x, wv = t >> 6, l = t & 63;
    const int rbase = blockIdx.y * 32;
    const int prow0 = blockIdx.x * 32;

    // staging geometry
    size_t ag[2], wg[2];
    unsigned al[2], wl[2];
    #pragma unroll
    for (int c = 0; c < 2; ++c) {
        int idx = (c * 4 + wv) * 64 + l;
        int row = idx >> 4, kb = (idx & 15) << 4;
        int sw = kb ^ ((row & 7) << 4);
        ag[c] = (size_t)(rbase + row) * U_ + (sw >> 1);
        al[c] = (c * 4 + wv) * 1024;
        wg[c] = (size_t)(prow0 + row) * U_ + (sw >> 1);
        wl[c] = 8192 + (c * 4 + wv) * 1024;
    }
    // compute geometry
    const int rq = wv & 1, ch = wv >> 1;
    const int lr = l & 15, lkb = (l >> 4) << 4;
    int aoff[4], woff[4];
    #pragma unroll
    for (int ks = 0; ks < 4; ++ks) {
        int kb = ks * 64 + lkb;
        int ar = rq * 16 + lr, wr = ch * 16 + lr;
        aoff[ks] = ar * 256 + (kb ^ ((ar & 7) << 4));
        woff[ks] = 8192 + wr * 256 + (kb ^ ((wr & 7) << 4));
    }

    auto issue = [&](int tt) {
        const int k0 = tt * 128;
        char* sb = stg + (tt % 3) * 16384;
        gld16(A + ag[0] + k0, sb + al[0]);
        gld16(A + ag[1] + k0, sb + al[1]);
        gld16(W + wg[0] + k0, sb + wl[0]);
        gld16(W + wg[1] + k0, sb + wl[1]);
    };

    f32x4 acc = {};
    issue(0);
    issue(1);
    for (int tt = 0; tt < 16; ++tt) {
        if (tt < 15) asm volatile("s_waitcnt vmcnt(4)" ::: "memory");
        else         asm volatile("s_waitcnt vmcnt(0)" ::: "memory");
        __builtin_amdgcn_s_barrier();
        if (tt + 2 < 16) issue(tt + 2);
        const char* sb = stg + (tt % 3) * 16384;
        #pragma unroll
        for (int ks = 0; ks < 4; ++ks) {
            bf16x8 av = *(const bf16x8*)(sb + aoff[ks]);
            bf16x8 wf = *(const bf16x8*)(sb + woff[ks]);
            acc = MFMA(av, wf, acc);
        }
    }

    const int l4 = (l >> 4) << 2;
    if (MODE == 1) {
        // write partial S tile to zg[batch][pcol]
        #pragma unroll
        for (int r = 0; r < 4; ++r) {
            int row = rbase + rq * 16 + l4 + r;
            int col = prow0 + ch * 16 + lr;
            __builtin_nontemporal_store(acc[r], &zg[(size_t)row * G4_ + col]);
        }
        return;
    }

    #pragma unroll
    for (int r = 0; r < 4; ++r) {
        float v = acc[r];
        if (MODE == 2) {
            int row = rbase + rq * 16 + l4 + r;
            int col = prow0 + ch * 16 + lr;
            v += __builtin_nontemporal_load(&zg[(size_t)row * G4_ + col]);
        }
        sg[rq * 16 + l4 + r][ch * 16 + lr] = v;
    }
    __syncthreads();

    // gate: 32 rows x 8 units with 256 threads
    const int bl = t >> 3, uu = t & 7;
    const int b = rbase + bl, u = blockIdx.x * 8 + uu;
    float g[4];
    #pragma unroll
    for (int gi = 0; gi < 4; ++gi) {
        float base = (MODE == 0) ? xk0base[(size_t)b * G4_ + gi * 2048 + u]
                                 : bias[gi * 2048 + u];
        g[gi] = sg[bl][gi * 8 + uu] + base;
    }
    float* cp = cst + (size_t)b * U_ + u;
    const float c  = *cp;
    const float cn = sigf(g[1]) * c + sigf(g[0]) * tanhf(g[2]);
    const float hn = sigf(g[3]) * tanhf(cn);
    *cp = cn;
    hNew[(size_t)b * U_ + u] = f2bf(hn);
}

// Launch A: z=0 -> layer0 rk+gate; z=1/2 -> zg_l = h_l_old @ rk_l (write partials)
__global__ __launch_bounds__(256) void recA(
    const unsigned short* __restrict__ h0old, const unsigned short* __restrict__ h1old,
    const unsigned short* __restrict__ h2old,
    const unsigned short* __restrict__ rk0P, const unsigned short* __restrict__ rk1P,
    const unsigned short* __restrict__ rk2P,
    const float* __restrict__ xk0,
    float* __restrict__ zg1, float* __restrict__ zg2,
    float* __restrict__ cst0, unsigned short* __restrict__ h0new)
{
    const int z = blockIdx.z;
    if (z == 0)
        lstm_phase<0>(h0old, rk0P, xk0, nullptr, nullptr, cst0, h0new);
    else if (z == 1)
        lstm_phase<1>(h1old, rk1P, nullptr, nullptr, zg1, nullptr, nullptr);
    else
        lstm_phase<1>(h2old, rk2P, nullptr, nullptr, zg2, nullptr, nullptr);
}

// Launch B/C: S = xNew @ kP + zg + bias -> gate
__global__ __launch_bounds__(256) void kgate(
    const unsigned short* __restrict__ xNew, const unsigned short* __restrict__ kP,
    float* __restrict__ zg, const float* __restrict__ bias,
    float* __restrict__ cst, unsigned short* __restrict__ hNew)
{
    lstm_phase<2>(xNew, kP, nullptr, bias, zg, cst, hNew);
}

// ---------------- batched output projection: ONE GEMM after the time loop ----------------
__global__ __launch_bounds__(256) void outproj_all(const unsigned short* __restrict__ h2h,
                                                   const unsigned short* __restrict__ w_outT,
                                                   const float* __restrict__ b_out,
                                                   float* __restrict__ out)
{
    const int t = threadIdx.x, wv = t >> 6, l = t & 63;
    const int m0 = blockIdx.x * 64 + wv * 16;
    const int lr = l & 15, lk = (l >> 4) * 8;
    const unsigned short* ap = h2h + (size_t)(m0 + lr) * U_ + lk;
    f32x4 acc[6] = {};
    for (int kt = 0; kt < U_; kt += 32) {
        bf16x8 af = *(const bf16x8*)(ap + kt);
        #pragma unroll
        for (int n = 0; n < 6; ++n) {
            bf16x8 wf = *(const bf16x8*)(w_outT + (size_t)(n * 16 + lr) * U_ + kt + lk);
            acc[n] = MFMA(af, wf, acc[n]);
        }
    }
    const int l4 = (l >> 4) * 4;
    #pragma unroll
    for (int n = 0; n < 6; ++n) {
        const int col = n * 16 + lr;
        if (col < DIN_) {
            #pragma unroll
            for (int r = 0; r < 4; ++r) {
                int row = m0 + l4 + r;                  // = tstep*64 + b
                int tt = row >> 6, b = row & 63;
                out[((size_t)b * T_ + tt) * DIN_ + col] = acc[n][r] + b_out[col];
            }
        }
    }
}

extern "C" void kernel_launch(void* const* d_in, const int* in_sizes, int n_in,
                              void* d_out, int out_size, void* d_ws, size_t ws_size,
                              hipStream_t stream)
{
    const float* z      = (const float*)d_in[0];
    const float* w_init = (const float*)d_in[1];
    const float* b_init = (const float*)d_in[2];
    const float* k0     = (const float*)d_in[3];
    const float* rk0    = (const float*)d_in[4];
    const float* b0     = (const float*)d_in[5];
    const float* k1     = (const float*)d_in[6];
    const float* rk1    = (const float*)d_in[7];
    const float* b1     = (const float*)d_in[8];
    const float* k2     = (const float*)d_in[9];
    const float* rk2    = (const float*)d_in[10];
    const float* b2     = (const float*)d_in[11];
    const float* w_out  = (const float*)d_in[12];
    const float* b_out  = (const float*)d_in[13];
    float* out = (float*)d_out;
    (void)in_sizes; (void)n_in; (void)out_size; (void)ws_size;

    // workspace carve-up (256B aligned), total ~210 MB
    size_t off = 0;
    char* base = (char*)d_ws;
    auto alloc = [&](size_t bytes) { void* p = base + off; off += (bytes + 255) & ~(size_t)255; return p; };
    unsigned short* rk0P = (unsigned short*)alloc((size_t)U_ * G4_ * 2);
    unsigned short* rk1P = (unsigned short*)alloc((size_t)U_ * G4_ * 2);
    unsigned short* rk2P = (unsigned short*)alloc((size_t)U_ * G4_ * 2);
    unsigned short* k1P  = (unsigned short*)alloc((size_t)U_ * G4_ * 2);
    unsigned short* k2P  = (unsigned short*)alloc((size_t)U_ * G4_ * 2);
    unsigned short* wiT  = (unsigned short*)alloc((size_t)STLD * Z_ * 2);
    unsigned short* k0T  = (unsigned short*)alloc((size_t)G4_ * Z_ * 2);
    unsigned short* woT  = (unsigned short*)alloc((size_t)96 * U_ * 2);
    unsigned short* zb   = (unsigned short*)alloc((size_t)B_ * Z_ * 2);
    unsigned short* hb0[2], *hb1[2];
    for (int p = 0; p < 2; ++p) hb0[p] = (unsigned short*)alloc((size_t)B_ * U_ * 2);
    for (int p = 0; p < 2; ++p) hb1[p] = (unsigned short*)alloc((size_t)B_ * U_ * 2);
    unsigned short* h2hist = (unsigned short*)alloc((size_t)(T_ + 1) * B_ * U_ * 2);
    float* st   = (float*)alloc((size_t)B_ * STLD * 4);
    float* xk0  = (float*)alloc((size_t)B_ * G4_ * 4);
    float* zg1  = (float*)alloc((size_t)B_ * G4_ * 4);
    float* zg2  = (float*)alloc((size_t)B_ * G4_ * 4);
    float* cst0 = (float*)alloc((size_t)B_ * U_ * 4);
    float* cst1 = (float*)alloc((size_t)B_ * U_ * 4);
    float* cst2 = (float*)alloc((size_t)B_ * U_ * 4);

    // --- one-time conversions ---
    transpose_cvt_packed<<<dim3(G4_ / 32, U_ / 32), 256, 0, stream>>>(rk0, rk0P);
    transpose_cvt_packed<<<dim3(G4_ / 32, U_ / 32), 256, 0, stream>>>(rk1, rk1P);
    transpose_cvt_packed<<<dim3(G4_ / 32, U_ / 32), 256, 0, stream>>>(rk2, rk2P);
    transpose_cvt_packed<<<dim3(G4_ / 32, U_ / 32), 256, 0, stream>>>(k1, k1P);
    transpose_cvt_packed<<<dim3(G4_ / 32, U_ / 32), 256, 0, stream>>>(k2, k2P);
    transpose_cvt<<<dim3(STLD / 32, Z_ / 32), 256, 0, stream>>>(w_init, wiT, Z_, STLD, 0);
    transpose_cvt<<<dim3(G4_ / 32, Z_ / 32), 256, 0, stream>>>(k0, k0T, Z_, G4_, DIN_);
    wout_cvt<<<dim3(96 * U_ / 256), 256, 0, stream>>>(w_out, woT);
    cvt_z<<<dim3(B_ * Z_ / 256), 256, 0, stream>>>(z, zb);

    // --- setup: st = zb @ wiT^T + b_init ; xk0 = zb @ k0T^T + b0 ---
    gemm_plain<<<dim3(STLD / 64), 256, 0, stream>>>(zb, Z_, wiT, b_init, st, STLD);
    gemm_plain<<<dim3(G4_ / 64), 256, 0, stream>>>(zb, Z_, k0T, b0, xk0, G4_);
    hcinit<<<dim3(3 * B_ * U_ / 256), 256, 0, stream>>>(st, hb0[0], hb1[0], h2hist,
                                                        cst0, cst1, cst2);

    // --- time loop: 3 launches/step (rk GEMMs of all layers overlapped in recA) ---
    for (int tstep = 0; tstep < T_; ++tstep) {
        const int p = tstep & 1;
        recA<<<dim3(U_ / 8, 2, 3), 256, 0, stream>>>(
            hb0[p], hb1[p], h2hist + (size_t)tstep * B_ * U_,
            rk0P, rk1P, rk2P, xk0, zg1, zg2, cst0, hb0[p ^ 1]);
        kgate<<<dim3(U_ / 8, 2), 256, 0, stream>>>(hb0[p ^ 1], k1P, zg1, b1, cst1, hb1[p ^ 1]);
        kgate<<<dim3(U_ / 8, 2), 256, 0, stream>>>(hb1[p ^ 1], k2P, zg2, b2, cst2,
                                                   h2hist + (size_t)(tstep + 1) * B_ * U_);
    }
    // --- all 32 output projections in one GEMM ---
    outproj_all<<<dim3(T_ * B_ / 64), 256, 0, stream>>>(h2hist + (size_t)B_ * U_, woT, b_out, out);
}

// Round 12
// 1966.281 us; speedup vs baseline: 1.5412x; 1.5412x over previous
//
#include <hip/hip_runtime.h>
#include <cstdint>

// Problem constants
#define B_   64
#define Z_   512
#define U_   2048
#define T_   32
#define DIN_ 90
#define G4_  8192      // 4*U
#define STLD 12288     // setup GEMM output row stride: h at +l*4096, c at +l*4096+2048

using bf16x8 = __attribute__((ext_vector_type(8))) short;   // 8 bf16 = 4 VGPRs
using f32x4  = __attribute__((ext_vector_type(4))) float;

#define MFMA(a, b, c) __builtin_amdgcn_mfma_f32_16x16x32_bf16((a), (b), (c), 0, 0, 0)

__device__ __forceinline__ unsigned short f2bf(float f) {
    unsigned int u = __float_as_uint(f);
    unsigned int r = (u + 0x7FFFu + ((u >> 16) & 1u)) >> 16;   // RNE
    return (unsigned short)r;
}
__device__ __forceinline__ float sigf(float x) { return 1.f / (1.f + expf(-x)); }

// async global->LDS, 16 B per lane; LDS dest is wave-uniform base + lane*16
__device__ __forceinline__ void gld16(const void* g, void* l) {
    __builtin_amdgcn_global_load_lds(
        (const __attribute__((address_space(1))) unsigned int*)g,
        (__attribute__((address_space(3))) unsigned int*)l, 16, 0, 0);
}

// ======== staged K=2048 GEMM core as macros (LDS stays at kernel scope; ========
// ======== passing __shared__ pointers through fn params ICEs clang r11)  ========
// Requires in scope: stg, t, wv, l, rbase, prow0, rq, ch, lr.
// Block 256 = 4 waves (rq row-half, ch col-half), tile 32 rows x 32 packed cols,
// KT=128, 3 LDS stages, counted vmcnt(4). T2 XOR swizzle via pre-swizzled source.
#define GEMM_PROLOG()                                                        \
    size_t ag0, ag1, wg0, wg1; unsigned al0, al1, wl0, wl1;                  \
    {                                                                        \
        int idx0 = wv * 64 + l;                                              \
        int row0 = idx0 >> 4, kb0 = (idx0 & 15) << 4;                        \
        int sw0 = kb0 ^ ((row0 & 7) << 4);                                   \
        ag0 = (size_t)(rbase + row0) * U_ + (sw0 >> 1);                      \
        al0 = wv * 1024;                                                     \
        wg0 = (size_t)(prow0 + row0) * U_ + (sw0 >> 1);                      \
        wl0 = 8192 + wv * 1024;                                              \
        int idx1 = (4 + wv) * 64 + l;                                        \
        int row1 = idx1 >> 4, kb1 = (idx1 & 15) << 4;                        \
        int sw1 = kb1 ^ ((row1 & 7) << 4);                                   \
        ag1 = (size_t)(rbase + row1) * U_ + (sw1 >> 1);                      \
        al1 = (4 + wv) * 1024;                                               \
        wg1 = (size_t)(prow0 + row1) * U_ + (sw1 >> 1);                      \
        wl1 = 8192 + (4 + wv) * 1024;                                        \
    }                                                                        \
    int aoff[4], woff[4];                                                    \
    {                                                                        \
        const int lkb = (l >> 4) << 4;                                       \
        _Pragma("unroll")                                                    \
        for (int ks = 0; ks < 4; ++ks) {                                     \
            int kb = ks * 64 + lkb;                                          \
            int ar = rq * 16 + lr, wr = ch * 16 + lr;                        \
            aoff[ks] = ar * 256 + (kb ^ ((ar & 7) << 4));                    \
            woff[ks] = 8192 + wr * 256 + (kb ^ ((wr & 7) << 4));             \
        }                                                                    \
    }

#define ISSUE(Ap, Wp, tt) do {                                               \
        const int k0_ = (tt) * 128;                                         \
        char* sb_ = stg + ((tt) % 3) * 16384;                               \
        gld16((Ap) + ag0 + k0_, sb_ + al0);                                 \
        gld16((Ap) + ag1 + k0_, sb_ + al1);                                 \
        gld16((Wp) + wg0 + k0_, sb_ + wl0);                                 \
        gld16((Wp) + wg1 + k0_, sb_ + wl1);                                 \
    } while (0)

#define GEMM_LOOP(Ap, Wp)                                                    \
    ISSUE(Ap, Wp, 0);                                                        \
    ISSUE(Ap, Wp, 1);                                                        \
    for (int tt = 0; tt < 16; ++tt) {                                        \
        if (tt < 15) asm volatile("s_waitcnt vmcnt(4)" ::: "memory");        \
        else         asm volatile("s_waitcnt vmcnt(0)" ::: "memory");        \
        __builtin_amdgcn_s_barrier();                                        \
        if (tt + 2 < 16) ISSUE(Ap, Wp, tt + 2);                              \
        const char* sb = stg + (tt % 3) * 16384;                             \
        _Pragma("unroll")                                                    \
        for (int ks = 0; ks < 4; ++ks) {                                     \
            bf16x8 av = *(const bf16x8*)(sb + aoff[ks]);                     \
            bf16x8 wf = *(const bf16x8*)(sb + woff[ks]);                     \
            acc = MFMA(av, wf, acc);                                         \
        }                                                                    \
    }

// ---------------- one-time weight prep ----------------

// Plain transpose: Wt[n*K + k] = bf16(W[(row_off+k)*N + n])
__global__ __launch_bounds__(256) void transpose_cvt(const float* __restrict__ W,
                                                     unsigned short* __restrict__ Wt,
                                                     int K, int N, int row_off)
{
    __shared__ float tile[32][33];
    const int nb = blockIdx.x * 32, kb = blockIdx.y * 32;
    const int tx = threadIdx.x & 31, ty = threadIdx.x >> 5;   // 32 x 8
    #pragma unroll
    for (int i = 0; i < 4; ++i)
        tile[ty + i * 8][tx] = W[(size_t)(row_off + kb + ty + i * 8) * N + nb + tx];
    __syncthreads();
    #pragma unroll
    for (int i = 0; i < 4; ++i)
        Wt[(size_t)(nb + ty + i * 8) * K + kb + tx] = f2bf(tile[tx][ty + i * 8]);
}

// Packed transpose: original col n = g*2048+u -> packed row (u>>3)*32 + g*8 + (u&7).
__global__ __launch_bounds__(256) void transpose_cvt_packed(const float* __restrict__ W,
                                                            unsigned short* __restrict__ Wt)
{
    __shared__ float tile[32][33];
    const int nb = blockIdx.x * 32, kb = blockIdx.y * 32;   // N=8192, K=2048
    const int tx = threadIdx.x & 31, ty = threadIdx.x >> 5;
    #pragma unroll
    for (int i = 0; i < 4; ++i)
        tile[ty + i * 8][tx] = W[(size_t)(kb + ty + i * 8) * G4_ + nb + tx];
    __syncthreads();
    #pragma unroll
    for (int i = 0; i < 4; ++i) {
        int n = nb + ty + i * 8;
        int g = n >> 11, u = n & 2047;
        int prow = ((u >> 3) << 5) + (g << 3) + (u & 7);
        Wt[(size_t)prow * U_ + kb + tx] = f2bf(tile[tx][ty + i * 8]);
    }
}

// w_outT[d][k] = bf16(w_out[k*90+d]) for d<90, else 0   (96 x 2048)
__global__ __launch_bounds__(256) void wout_cvt(const float* __restrict__ w_out,
                                                unsigned short* __restrict__ w_outT)
{
    int i = blockIdx.x * 256 + threadIdx.x;        // 96*2048
    int d = i >> 11, k = i & 2047;
    w_outT[i] = (d < DIN_) ? f2bf(w_out[(size_t)k * DIN_ + d]) : (unsigned short)0;
}

__global__ __launch_bounds__(256) void cvt_z(const float* __restrict__ z,
                                             unsigned short* __restrict__ zb)
{
    int i = blockIdx.x * 256 + threadIdx.x;        // 64*512
    zb[i] = f2bf(z[i]);
}

// initial h (bf16) and c (fp32) from the setup GEMM output st
__global__ __launch_bounds__(256) void hcinit(const float* __restrict__ st,
                                              unsigned short* __restrict__ h0,
                                              unsigned short* __restrict__ h1,
                                              unsigned short* __restrict__ h2s0,
                                              float* __restrict__ c0,
                                              float* __restrict__ c1,
                                              float* __restrict__ c2)
{
    int idx = blockIdx.x * 256 + threadIdx.x;      // 3*64*2048
    int u = idx & 2047, b = (idx >> 11) & 63, ly = idx >> 17;
    float hv = st[(size_t)b * STLD + ly * 4096 + u];
    float cv = st[(size_t)b * STLD + ly * 4096 + 2048 + u];
    unsigned short* h = (ly == 0) ? h0 : (ly == 1) ? h1 : h2s0;
    float* c = (ly == 0) ? c0 : (ly == 1) ? c1 : c2;
    h[(size_t)b * 2048 + u] = f2bf(hv);
    c[(size_t)b * 2048 + u] = cv;
}

// ---------------- setup GEMMs (K=512): out[64 x N] = A @ Wt^T + bias ----------------
__global__ __launch_bounds__(256) void gemm_plain(const unsigned short* __restrict__ A, int K,
                                                  const unsigned short* __restrict__ Wt,
                                                  const float* __restrict__ bias,
                                                  float* __restrict__ out, int ldo)
{
    const int t = threadIdx.x, wv = t >> 6, l = t & 63;
    const int wm = (wv >> 1) * 32, n0 = blockIdx.x * 64 + (wv & 1) * 32;
    const int lr = l & 15, lk = (l >> 4) * 8;
    f32x4 acc[2][2] = {};
    for (int kt = 0; kt < K; kt += 32) {
        bf16x8 a0 = *(const bf16x8*)(A + (size_t)(wm + lr) * K + kt + lk);
        bf16x8 a1 = *(const bf16x8*)(A + (size_t)(wm + 16 + lr) * K + kt + lk);
        bf16x8 w0 = *(const bf16x8*)(Wt + (size_t)(n0 + lr) * K + kt + lk);
        bf16x8 w1 = *(const bf16x8*)(Wt + (size_t)(n0 + 16 + lr) * K + kt + lk);
        acc[0][0] = MFMA(a0, w0, acc[0][0]);
        acc[0][1] = MFMA(a0, w1, acc[0][1]);
        acc[1][0] = MFMA(a1, w0, acc[1][0]);
        acc[1][1] = MFMA(a1, w1, acc[1][1]);
    }
    #pragma unroll
    for (int mi = 0; mi < 2; ++mi)
        #pragma unroll
        for (int ni = 0; ni < 2; ++ni)
            #pragma unroll
            for (int r = 0; r < 4; ++r) {
                int row = wm + mi * 16 + (l >> 4) * 4 + r;
                int col = n0 + ni * 16 + lr;
                out[(size_t)row * ldo + col] = acc[mi][ni][r] + bias[col];
            }
}

// Launch A: z=0 -> layer0 rk+gate (uses xk0 base); z=1/2 -> zg_l = h_l_old @ rk_l
__global__ __launch_bounds__(256) void recA(
    const unsigned short* __restrict__ h0old, const unsigned short* __restrict__ h1old,
    const unsigned short* __restrict__ h2old,
    const unsigned short* __restrict__ rk0P, const unsigned short* __restrict__ rk1P,
    const unsigned short* __restrict__ rk2P,
    const float* __restrict__ xk0,
    float* __restrict__ zg1, float* __restrict__ zg2,
    float* __restrict__ cst0, unsigned short* __restrict__ h0new)
{
    __shared__ char  stg[3 * 16384];
    __shared__ float sg[32][33];
    const int t = threadIdx.x, wv = t >> 6, l = t & 63;
    const int rbase = blockIdx.y * 32, prow0 = blockIdx.x * 32;
    const int rq = wv & 1, ch = wv >> 1, lr = l & 15;
    const int z = blockIdx.z;
    const unsigned short* A = (z == 0) ? h0old : (z == 1) ? h1old : h2old;
    const unsigned short* W = (z == 0) ? rk0P : (z == 1) ? rk1P : rk2P;

    GEMM_PROLOG();
    f32x4 acc = {};
    GEMM_LOOP(A, W);

    const int l4 = (l >> 4) << 2;
    if (z != 0) {
        float* zg = (z == 1) ? zg1 : zg2;
        #pragma unroll
        for (int r = 0; r < 4; ++r) {
            int row = rbase + rq * 16 + l4 + r;
            int col = prow0 + ch * 16 + lr;
            __builtin_nontemporal_store(acc[r], &zg[(size_t)row * G4_ + col]);
        }
        return;
    }
    #pragma unroll
    for (int r = 0; r < 4; ++r)
        sg[rq * 16 + l4 + r][ch * 16 + lr] = acc[r];
    __syncthreads();

    const int bl = t >> 3, uu = t & 7;
    const int b = rbase + bl, u = blockIdx.x * 8 + uu;
    float g[4];
    #pragma unroll
    for (int gi = 0; gi < 4; ++gi)
        g[gi] = sg[bl][gi * 8 + uu] + xk0[(size_t)b * G4_ + gi * 2048 + u];
    float* cp = cst0 + (size_t)b * U_ + u;
    const float c  = *cp;
    const float cn = sigf(g[1]) * c + sigf(g[0]) * tanhf(g[2]);
    const float hn = sigf(g[3]) * tanhf(cn);
    *cp = cn;
    h0new[(size_t)b * U_ + u] = f2bf(hn);
}

// Launch B/C: S = xNew @ kP + zg + bias -> gate -> cst, hNew
__global__ __launch_bounds__(256) void kgate(
    const unsigned short* __restrict__ xNew, const unsigned short* __restrict__ kP,
    const float* __restrict__ zgin, const float* __restrict__ bias,
    float* __restrict__ cst, unsigned short* __restrict__ hNew)
{
    __shared__ char  stg[3 * 16384];
    __shared__ float sg[32][33];
    const int t = threadIdx.x, wv = t >> 6, l = t & 63;
    const int rbase = blockIdx.y * 32, prow0 = blockIdx.x * 32;
    const int rq = wv & 1, ch = wv >> 1, lr = l & 15;

    GEMM_PROLOG();
    f32x4 acc = {};
    GEMM_LOOP(xNew, kP);

    const int l4 = (l >> 4) << 2;
    #pragma unroll
    for (int r = 0; r < 4; ++r) {
        int row = rbase + rq * 16 + l4 + r;
        int col = prow0 + ch * 16 + lr;
        sg[rq * 16 + l4 + r][ch * 16 + lr] =
            acc[r] + __builtin_nontemporal_load(&zgin[(size_t)row * G4_ + col]);
    }
    __syncthreads();

    const int bl = t >> 3, uu = t & 7;
    const int b = rbase + bl, u = blockIdx.x * 8 + uu;
    float g[4];
    #pragma unroll
    for (int gi = 0; gi < 4; ++gi)
        g[gi] = sg[bl][gi * 8 + uu] + bias[gi * 2048 + u];
    float* cp = cst + (size_t)b * U_ + u;
    const float c  = *cp;
    const float cn = sigf(g[1]) * c + sigf(g[0]) * tanhf(g[2]);
    const float hn = sigf(g[3]) * tanhf(cn);
    *cp = cn;
    hNew[(size_t)b * U_ + u] = f2bf(hn);
}

// ---------------- batched output projection: ONE GEMM after the time loop ----------------
__global__ __launch_bounds__(256) void outproj_all(const unsigned short* __restrict__ h2h,
                                                   const unsigned short* __restrict__ w_outT,
                                                   const float* __restrict__ b_out,
                                                   float* __restrict__ out)
{
    const int t = threadIdx.x, wv = t >> 6, l = t & 63;
    const int m0 = blockIdx.x * 64 + wv * 16;
    const int lr = l & 15, lk = (l >> 4) * 8;
    const unsigned short* ap = h2h + (size_t)(m0 + lr) * U_ + lk;
    f32x4 acc[6] = {};
    for (int kt = 0; kt < U_; kt += 32) {
        bf16x8 af = *(const bf16x8*)(ap + kt);
        #pragma unroll
        for (int n = 0; n < 6; ++n) {
            bf16x8 wf = *(const bf16x8*)(w_outT + (size_t)(n * 16 + lr) * U_ + kt + lk);
            acc[n] = MFMA(af, wf, acc[n]);
        }
    }
    const int l4 = (l >> 4) * 4;
    #pragma unroll
    for (int n = 0; n < 6; ++n) {
        const int col = n * 16 + lr;
        if (col < DIN_) {
            #pragma unroll
            for (int r = 0; r < 4; ++r) {
                int row = m0 + l4 + r;                  // = tstep*64 + b
                int tt = row >> 6, b = row & 63;
                out[((size_t)b * T_ + tt) * DIN_ + col] = acc[n][r] + b_out[col];
            }
        }
    }
}

extern "C" void kernel_launch(void* const* d_in, const int* in_sizes, int n_in,
                              void* d_out, int out_size, void* d_ws, size_t ws_size,
                              hipStream_t stream)
{
    const float* z      = (const float*)d_in[0];
    const float* w_init = (const float*)d_in[1];
    const float* b_init = (const float*)d_in[2];
    const float* k0     = (const float*)d_in[3];
    const float* rk0    = (const float*)d_in[4];
    const float* b0     = (const float*)d_in[5];
    const float* k1     = (const float*)d_in[6];
    const float* rk1    = (const float*)d_in[7];
    const float* b1     = (const float*)d_in[8];
    const float* k2     = (const float*)d_in[9];
    const float* rk2    = (const float*)d_in[10];
    const float* b2     = (const float*)d_in[11];
    const float* w_out  = (const float*)d_in[12];
    const float* b_out  = (const float*)d_in[13];
    float* out = (float*)d_out;
    (void)in_sizes; (void)n_in; (void)out_size; (void)ws_size;

    // workspace carve-up (256B aligned), total ~210 MB
    size_t off = 0;
    char* base = (char*)d_ws;
    auto alloc = [&](size_t bytes) { void* p = base + off; off += (bytes + 255) & ~(size_t)255; return p; };
    unsigned short* rk0P = (unsigned short*)alloc((size_t)U_ * G4_ * 2);
    unsigned short* rk1P = (unsigned short*)alloc((size_t)U_ * G4_ * 2);
    unsigned short* rk2P = (unsigned short*)alloc((size_t)U_ * G4_ * 2);
    unsigned short* k1P  = (unsigned short*)alloc((size_t)U_ * G4_ * 2);
    unsigned short* k2P  = (unsigned short*)alloc((size_t)U_ * G4_ * 2);
    unsigned short* wiT  = (unsigned short*)alloc((size_t)STLD * Z_ * 2);
    unsigned short* k0T  = (unsigned short*)alloc((size_t)G4_ * Z_ * 2);
    unsigned short* woT  = (unsigned short*)alloc((size_t)96 * U_ * 2);
    unsigned short* zb   = (unsigned short*)alloc((size_t)B_ * Z_ * 2);
    unsigned short* hb0[2], *hb1[2];
    for (int p = 0; p < 2; ++p) hb0[p] = (unsigned short*)alloc((size_t)B_ * U_ * 2);
    for (int p = 0; p < 2; ++p) hb1[p] = (unsigned short*)alloc((size_t)B_ * U_ * 2);
    unsigned short* h2hist = (unsigned short*)alloc((size_t)(T_ + 1) * B_ * U_ * 2);
    float* st   = (float*)alloc((size_t)B_ * STLD * 4);
    float* xk0  = (float*)alloc((size_t)B_ * G4_ * 4);
    float* zg1  = (float*)alloc((size_t)B_ * G4_ * 4);
    float* zg2  = (float*)alloc((size_t)B_ * G4_ * 4);
    float* cst0 = (float*)alloc((size_t)B_ * U_ * 4);
    float* cst1 = (float*)alloc((size_t)B_ * U_ * 4);
    float* cst2 = (float*)alloc((size_t)B_ * U_ * 4);

    // --- one-time conversions ---
    transpose_cvt_packed<<<dim3(G4_ / 32, U_ / 32), 256, 0, stream>>>(rk0, rk0P);
    transpose_cvt_packed<<<dim3(G4_ / 32, U_ / 32), 256, 0, stream>>>(rk1, rk1P);
    transpose_cvt_packed<<<dim3(G4_ / 32, U_ / 32), 256, 0, stream>>>(rk2, rk2P);
    transpose_cvt_packed<<<dim3(G4_ / 32, U_ / 32), 256, 0, stream>>>(k1, k1P);
    transpose_cvt_packed<<<dim3(G4_ / 32, U_ / 32), 256, 0, stream>>>(k2, k2P);
    transpose_cvt<<<dim3(STLD / 32, Z_ / 32), 256, 0, stream>>>(w_init, wiT, Z_, STLD, 0);
    transpose_cvt<<<dim3(G4_ / 32, Z_ / 32), 256, 0, stream>>>(k0, k0T, Z_, G4_, DIN_);
    wout_cvt<<<dim3(96 * U_ / 256), 256, 0, stream>>>(w_out, woT);
    cvt_z<<<dim3(B_ * Z_ / 256), 256, 0, stream>>>(z, zb);

    // --- setup: st = zb @ wiT^T + b_init ; xk0 = zb @ k0T^T + b0 ---
    gemm_plain<<<dim3(STLD / 64), 256, 0, stream>>>(zb, Z_, wiT, b_init, st, STLD);
    gemm_plain<<<dim3(G4_ / 64), 256, 0, stream>>>(zb, Z_, k0T, b0, xk0, G4_);
    hcinit<<<dim3(3 * B_ * U_ / 256), 256, 0, stream>>>(st, hb0[0], hb1[0], h2hist,
                                                        cst0, cst1, cst2);

    // --- time loop: 3 launches/step (rk GEMMs of all layers overlapped in recA) ---
    for (int tstep = 0; tstep < T_; ++tstep) {
        const int p = tstep & 1;
        recA<<<dim3(U_ / 8, 2, 3), 256, 0, stream>>>(
            hb0[p], hb1[p], h2hist + (size_t)tstep * B_ * U_,
            rk0P, rk1P, rk2P, xk0, zg1, zg2, cst0, hb0[p ^ 1]);
        kgate<<<dim3(U_ / 8, 2), 256, 0, stream>>>(hb0[p ^ 1], k1P, zg1, b1, cst1, hb1[p ^ 1]);
        kgate<<<dim3(U_ / 8, 2), 256, 0, stream>>>(hb1[p ^ 1], k2P, zg2, b2, cst2,
                                                   h2hist + (size_t)(tstep + 1) * B_ * U_);
    }
    // --- all 32 output projections in one GEMM ---
    outproj_all<<<dim3(T_ * B_ / 64), 256, 0, stream>>>(h2hist + (size_t)B_ * U_, woT, b_out, out);
}

// Round 13
// 1939.272 us; speedup vs baseline: 1.5627x; 1.0139x over previous
//
#include <hip/hip_runtime.h>
#include <cstdint>

// Problem constants
#define B_   64
#define Z_   512
#define U_   2048
#define T_   32
#define DIN_ 90
#define G4_  8192      // 4*U
#define STLD 12288     // setup GEMM output row stride: h at +l*4096, c at +l*4096+2048

using bf16x8 = __attribute__((ext_vector_type(8))) short;   // 8 bf16 = 4 VGPRs
using f32x4  = __attribute__((ext_vector_type(4))) float;

#define MFMA(a, b, c) __builtin_amdgcn_mfma_f32_16x16x32_bf16((a), (b), (c), 0, 0, 0)

__device__ __forceinline__ unsigned short f2bf(float f) {
    unsigned int u = __float_as_uint(f);
    unsigned int r = (u + 0x7FFFu + ((u >> 16) & 1u)) >> 16;   // RNE
    return (unsigned short)r;
}
__device__ __forceinline__ float sigf(float x) { return 1.f / (1.f + expf(-x)); }

// async global->LDS, 16 B per lane; LDS dest is wave-uniform base + lane*16
__device__ __forceinline__ void gld16(const void* g, void* l) {
    __builtin_amdgcn_global_load_lds(
        (const __attribute__((address_space(1))) unsigned int*)g,
        (__attribute__((address_space(3))) unsigned int*)l, 16, 0, 0);
}

// ======== staged K=2048 GEMM core as macros (LDS at kernel scope; passing ========
// ======== __shared__ pointers through fn params ICEs clang — r11 lesson)  ========
// Requires in scope: stg, t, wv, l, rbase, prow0, rq, ch, lr.
// Block 256 = 4 waves (rq row-half, ch col-half), tile 32 rows x 32 packed cols,
// KT=128, 3 LDS stages, counted vmcnt(4). T2 XOR swizzle via pre-swizzled source.
#define GEMM_PROLOG()                                                        \
    size_t ag0, ag1, wg0, wg1; unsigned al0, al1, wl0, wl1;                  \
    {                                                                        \
        int idx0 = wv * 64 + l;                                              \
        int row0 = idx0 >> 4, kb0 = (idx0 & 15) << 4;                        \
        int sw0 = kb0 ^ ((row0 & 7) << 4);                                   \
        ag0 = (size_t)(rbase + row0) * U_ + (sw0 >> 1);                      \
        al0 = wv * 1024;                                                     \
        wg0 = (size_t)(prow0 + row0) * U_ + (sw0 >> 1);                      \
        wl0 = 8192 + wv * 1024;                                              \
        int idx1 = (4 + wv) * 64 + l;                                        \
        int row1 = idx1 >> 4, kb1 = (idx1 & 15) << 4;                        \
        int sw1 = kb1 ^ ((row1 & 7) << 4);                                   \
        ag1 = (size_t)(rbase + row1) * U_ + (sw1 >> 1);                      \
        al1 = (4 + wv) * 1024;                                               \
        wg1 = (size_t)(prow0 + row1) * U_ + (sw1 >> 1);                      \
        wl1 = 8192 + (4 + wv) * 1024;                                        \
    }                                                                        \
    int aoff[4], woff[4];                                                    \
    {                                                                        \
        const int lkb = (l >> 4) << 4;                                       \
        _Pragma("unroll")                                                    \
        for (int ks = 0; ks < 4; ++ks) {                                     \
            int kb = ks * 64 + lkb;                                          \
            int ar = rq * 16 + lr, wr = ch * 16 + lr;                        \
            aoff[ks] = ar * 256 + (kb ^ ((ar & 7) << 4));                    \
            woff[ks] = 8192 + wr * 256 + (kb ^ ((wr & 7) << 4));             \
        }                                                                    \
    }

#define ISSUE(Ap, Wp, tt) do {                                               \
        const int k0_ = (tt) * 128;                                         \
        char* sb_ = stg + ((tt) % 3) * 16384;                               \
        gld16((Ap) + ag0 + k0_, sb_ + al0);                                 \
        gld16((Ap) + ag1 + k0_, sb_ + al1);                                 \
        gld16((Wp) + wg0 + k0_, sb_ + wl0);                                 \
        gld16((Wp) + wg1 + k0_, sb_ + wl1);                                 \
    } while (0)

#define GEMM_LOOP(Ap, Wp)                                                    \
    ISSUE(Ap, Wp, 0);                                                        \
    ISSUE(Ap, Wp, 1);                                                        \
    for (int tt = 0; tt < 16; ++tt) {                                        \
        if (tt < 15) asm volatile("s_waitcnt vmcnt(4)" ::: "memory");        \
        else         asm volatile("s_waitcnt vmcnt(0)" ::: "memory");        \
        __builtin_amdgcn_s_barrier();                                        \
        if (tt + 2 < 16) ISSUE(Ap, Wp, tt + 2);                              \
        const char* sb = stg + (tt % 3) * 16384;                             \
        _Pragma("unroll")                                                    \
        for (int ks = 0; ks < 4; ++ks) {                                     \
            bf16x8 av = *(const bf16x8*)(sb + aoff[ks]);                     \
            bf16x8 wf = *(const bf16x8*)(sb + woff[ks]);                     \
            acc = MFMA(av, wf, acc);                                         \
        }                                                                    \
    }

// mode-1 epilogue: nontemporal store S tile to ZG
#define EPI_ZG(ZG) do {                                                      \
        const int l4_ = (l >> 4) << 2;                                       \
        _Pragma("unroll")                                                    \
        for (int r = 0; r < 4; ++r) {                                        \
            int row = rbase + rq * 16 + l4_ + r;                             \
            int col = prow0 + ch * 16 + lr;                                  \
            __builtin_nontemporal_store(acc[r], &(ZG)[(size_t)row * G4_ + col]); \
        }                                                                    \
    } while (0)

// gate epilogues: fill sg (plain or +zg), then LSTM cell for 32 rows x 8 units
#define EPI_FILL_PLAIN() do {                                                \
        const int l4_ = (l >> 4) << 2;                                       \
        _Pragma("unroll")                                                    \
        for (int r = 0; r < 4; ++r)                                          \
            sg[rq * 16 + l4_ + r][ch * 16 + lr] = acc[r];                    \
    } while (0)

#define EPI_FILL_ZG(ZGIN) do {                                               \
        const int l4_ = (l >> 4) << 2;                                       \
        _Pragma("unroll")                                                    \
        for (int r = 0; r < 4; ++r) {                                        \
            int row = rbase + rq * 16 + l4_ + r;                             \
            int col = prow0 + ch * 16 + lr;                                  \
            sg[rq * 16 + l4_ + r][ch * 16 + lr] =                            \
                acc[r] + __builtin_nontemporal_load(&(ZGIN)[(size_t)row * G4_ + col]); \
        }                                                                    \
    } while (0)

// BASEEXPR may use b, u, gi
#define EPI_GATE(BASEEXPR, CST, HNEW) do {                                   \
        __syncthreads();                                                     \
        const int bl = t >> 3, uu = t & 7;                                   \
        const int b = rbase + bl, u = blockIdx.x * 8 + uu;                   \
        float g[4];                                                          \
        _Pragma("unroll")                                                    \
        for (int gi = 0; gi < 4; ++gi)                                       \
            g[gi] = sg[bl][gi * 8 + uu] + (BASEEXPR);                        \
        float* cp = (CST) + (size_t)b * U_ + u;                              \
        const float c_ = *cp;                                                \
        const float cn = sigf(g[1]) * c_ + sigf(g[0]) * tanhf(g[2]);         \
        const float hn = sigf(g[3]) * tanhf(cn);                             \
        *cp = cn;                                                            \
        (HNEW)[(size_t)b * U_ + u] = f2bf(hn);                               \
    } while (0)

// ---------------- one-time weight prep ----------------

__global__ __launch_bounds__(256) void transpose_cvt(const float* __restrict__ W,
                                                     unsigned short* __restrict__ Wt,
                                                     int K, int N, int row_off)
{
    __shared__ float tile[32][33];
    const int nb = blockIdx.x * 32, kb = blockIdx.y * 32;
    const int tx = threadIdx.x & 31, ty = threadIdx.x >> 5;   // 32 x 8
    #pragma unroll
    for (int i = 0; i < 4; ++i)
        tile[ty + i * 8][tx] = W[(size_t)(row_off + kb + ty + i * 8) * N + nb + tx];
    __syncthreads();
    #pragma unroll
    for (int i = 0; i < 4; ++i)
        Wt[(size_t)(nb + ty + i * 8) * K + kb + tx] = f2bf(tile[tx][ty + i * 8]);
}

// Packed transpose: original col n = g*2048+u -> packed row (u>>3)*32 + g*8 + (u&7).
__global__ __launch_bounds__(256) void transpose_cvt_packed(const float* __restrict__ W,
                                                            unsigned short* __restrict__ Wt)
{
    __shared__ float tile[32][33];
    const int nb = blockIdx.x * 32, kb = blockIdx.y * 32;   // N=8192, K=2048
    const int tx = threadIdx.x & 31, ty = threadIdx.x >> 5;
    #pragma unroll
    for (int i = 0; i < 4; ++i)
        tile[ty + i * 8][tx] = W[(size_t)(kb + ty + i * 8) * G4_ + nb + tx];
    __syncthreads();
    #pragma unroll
    for (int i = 0; i < 4; ++i) {
        int n = nb + ty + i * 8;
        int g = n >> 11, u = n & 2047;
        int prow = ((u >> 3) << 5) + (g << 3) + (u & 7);
        Wt[(size_t)prow * U_ + kb + tx] = f2bf(tile[tx][ty + i * 8]);
    }
}

// w_outT[d][k] = bf16(w_out[k*90+d]) for d<90, else 0   (96 x 2048)
__global__ __launch_bounds__(256) void wout_cvt(const float* __restrict__ w_out,
                                                unsigned short* __restrict__ w_outT)
{
    int i = blockIdx.x * 256 + threadIdx.x;        // 96*2048
    int d = i >> 11, k = i & 2047;
    w_outT[i] = (d < DIN_) ? f2bf(w_out[(size_t)k * DIN_ + d]) : (unsigned short)0;
}

__global__ __launch_bounds__(256) void cvt_z(const float* __restrict__ z,
                                             unsigned short* __restrict__ zb)
{
    int i = blockIdx.x * 256 + threadIdx.x;        // 64*512
    zb[i] = f2bf(z[i]);
}

// initial h (bf16) and c (fp32) from the setup GEMM output st
__global__ __launch_bounds__(256) void hcinit(const float* __restrict__ st,
                                              unsigned short* __restrict__ h0,
                                              unsigned short* __restrict__ h1,
                                              unsigned short* __restrict__ h2s0,
                                              float* __restrict__ c0,
                                              float* __restrict__ c1,
                                              float* __restrict__ c2)
{
    int idx = blockIdx.x * 256 + threadIdx.x;      // 3*64*2048
    int u = idx & 2047, b = (idx >> 11) & 63, ly = idx >> 17;
    float hv = st[(size_t)b * STLD + ly * 4096 + u];
    float cv = st[(size_t)b * STLD + ly * 4096 + 2048 + u];
    unsigned short* h = (ly == 0) ? h0 : (ly == 1) ? h1 : h2s0;
    float* c = (ly == 0) ? c0 : (ly == 1) ? c1 : c2;
    h[(size_t)b * 2048 + u] = f2bf(hv);
    c[(size_t)b * 2048 + u] = cv;
}

// ---------------- setup GEMMs (K=512): out[64 x N] = A @ Wt^T + bias ----------------
__global__ __launch_bounds__(256) void gemm_plain(const unsigned short* __restrict__ A, int K,
                                                  const unsigned short* __restrict__ Wt,
                                                  const float* __restrict__ bias,
                                                  float* __restrict__ out, int ldo)
{
    const int t = threadIdx.x, wv = t >> 6, l = t & 63;
    const int wm = (wv >> 1) * 32, n0 = blockIdx.x * 64 + (wv & 1) * 32;
    const int lr = l & 15, lk = (l >> 4) * 8;
    f32x4 acc[2][2] = {};
    for (int kt = 0; kt < K; kt += 32) {
        bf16x8 a0 = *(const bf16x8*)(A + (size_t)(wm + lr) * K + kt + lk);
        bf16x8 a1 = *(const bf16x8*)(A + (size_t)(wm + 16 + lr) * K + kt + lk);
        bf16x8 w0 = *(const bf16x8*)(Wt + (size_t)(n0 + lr) * K + kt + lk);
        bf16x8 w1 = *(const bf16x8*)(Wt + (size_t)(n0 + 16 + lr) * K + kt + lk);
        acc[0][0] = MFMA(a0, w0, acc[0][0]);
        acc[0][1] = MFMA(a0, w1, acc[0][1]);
        acc[1][0] = MFMA(a1, w0, acc[1][0]);
        acc[1][1] = MFMA(a1, w1, acc[1][1]);
    }
    #pragma unroll
    for (int mi = 0; mi < 2; ++mi)
        #pragma unroll
        for (int ni = 0; ni < 2; ++ni)
            #pragma unroll
            for (int r = 0; r < 4; ++r) {
                int row = wm + mi * 16 + (l >> 4) * 4 + r;
                int col = n0 + ni * 16 + lr;
                out[(size_t)row * ldo + col] = acc[mi][ni][r] + bias[col];
            }
}

// ---------------- pipelined step kernels ----------------
// X0 (t=0 prologue): z=0 -> rec0(0); z=1 -> rec1(0)
__global__ __launch_bounds__(256) void stepX0(
    const unsigned short* __restrict__ h0old, const unsigned short* __restrict__ rk0P,
    const float* __restrict__ xk0, float* __restrict__ cst0,
    unsigned short* __restrict__ h0new,
    const unsigned short* __restrict__ h1old, const unsigned short* __restrict__ rk1P,
    float* __restrict__ zg1)
{
    __shared__ char  stg[3 * 16384];
    __shared__ float sg[32][33];
    const int t = threadIdx.x, wv = t >> 6, l = t & 63;
    const int rbase = blockIdx.y * 32, prow0 = blockIdx.x * 32;
    const int rq = wv & 1, ch = wv >> 1, lr = l & 15;
    const int z = blockIdx.z;
    const unsigned short* A = (z == 0) ? h0old : h1old;
    const unsigned short* W = (z == 0) ? rk0P : rk1P;

    GEMM_PROLOG();
    f32x4 acc = {};
    GEMM_LOOP(A, W);

    if (z == 0) {
        EPI_FILL_PLAIN();
        EPI_GATE(xk0[(size_t)b * G4_ + gi * 2048 + u], cst0, h0new);
    } else {
        EPI_ZG(zg1);
    }
}

// X (t>=1): z=0 -> kgate2(t-1); z=1 -> rec0(t); z=2 -> rec1(t)
__global__ __launch_bounds__(256) void stepX(
    const unsigned short* __restrict__ h1prev, const unsigned short* __restrict__ k2P,
    const float* __restrict__ zg2in, const float* __restrict__ b2v,
    float* __restrict__ cst2, unsigned short* __restrict__ h2out,
    const unsigned short* __restrict__ h0old, const unsigned short* __restrict__ rk0P,
    const float* __restrict__ xk0, float* __restrict__ cst0,
    unsigned short* __restrict__ h0new,
    const unsigned short* __restrict__ h1old, const unsigned short* __restrict__ rk1P,
    float* __restrict__ zg1out)
{
    __shared__ char  stg[3 * 16384];
    __shared__ float sg[32][33];
    const int t = threadIdx.x, wv = t >> 6, l = t & 63;
    const int rbase = blockIdx.y * 32, prow0 = blockIdx.x * 32;
    const int rq = wv & 1, ch = wv >> 1, lr = l & 15;
    const int z = blockIdx.z;
    const unsigned short* A = (z == 0) ? h1prev : (z == 1) ? h0old : h1old;
    const unsigned short* W = (z == 0) ? k2P : (z == 1) ? rk0P : rk1P;

    GEMM_PROLOG();
    f32x4 acc = {};
    GEMM_LOOP(A, W);

    if (z == 0) {
        EPI_FILL_ZG(zg2in);
        EPI_GATE(b2v[gi * 2048 + u], cst2, h2out);
    } else if (z == 1) {
        EPI_FILL_PLAIN();
        EPI_GATE(xk0[(size_t)b * G4_ + gi * 2048 + u], cst0, h0new);
    } else {
        EPI_ZG(zg1out);
    }
}

// Y: z=0 -> rec2(t); z=1 -> kgate1(t)
__global__ __launch_bounds__(256) void stepY(
    const unsigned short* __restrict__ h2cur, const unsigned short* __restrict__ rk2P,
    float* __restrict__ zg2out,
    const unsigned short* __restrict__ h0new, const unsigned short* __restrict__ k1P,
    const float* __restrict__ zg1in, const float* __restrict__ b1v,
    float* __restrict__ cst1, unsigned short* __restrict__ h1new)
{
    __shared__ char  stg[3 * 16384];
    __shared__ float sg[32][33];
    const int t = threadIdx.x, wv = t >> 6, l = t & 63;
    const int rbase = blockIdx.y * 32, prow0 = blockIdx.x * 32;
    const int rq = wv & 1, ch = wv >> 1, lr = l & 15;
    const int z = blockIdx.z;
    const unsigned short* A = (z == 0) ? h2cur : h0new;
    const unsigned short* W = (z == 0) ? rk2P : k1P;

    GEMM_PROLOG();
    f32x4 acc = {};
    GEMM_LOOP(A, W);

    if (z == 0) {
        EPI_ZG(zg2out);
    } else {
        EPI_FILL_ZG(zg1in);
        EPI_GATE(b1v[gi * 2048 + u], cst1, h1new);
    }
}

// standalone kgate (epilogue: lone kgate2(31))
__global__ __launch_bounds__(256) void kgate(
    const unsigned short* __restrict__ xNew, const unsigned short* __restrict__ kP,
    const float* __restrict__ zgin, const float* __restrict__ bias,
    float* __restrict__ cst, unsigned short* __restrict__ hNew)
{
    __shared__ char  stg[3 * 16384];
    __shared__ float sg[32][33];
    const int t = threadIdx.x, wv = t >> 6, l = t & 63;
    const int rbase = blockIdx.y * 32, prow0 = blockIdx.x * 32;
    const int rq = wv & 1, ch = wv >> 1, lr = l & 15;

    GEMM_PROLOG();
    f32x4 acc = {};
    GEMM_LOOP(xNew, kP);

    EPI_FILL_ZG(zgin);
    EPI_GATE(bias[gi * 2048 + u], cst, hNew);
}

// ---------------- batched output projection: ONE GEMM after the time loop ----------------
__global__ __launch_bounds__(256) void outproj_all(const unsigned short* __restrict__ h2h,
                                                   const unsigned short* __restrict__ w_outT,
                                                   const float* __restrict__ b_out,
                                                   float* __restrict__ out)
{
    const int t = threadIdx.x, wv = t >> 6, l = t & 63;
    const int m0 = blockIdx.x * 64 + wv * 16;
    const int lr = l & 15, lk = (l >> 4) * 8;
    const unsigned short* ap = h2h + (size_t)(m0 + lr) * U_ + lk;
    f32x4 acc[6] = {};
    for (int kt = 0; kt < U_; kt += 32) {
        bf16x8 af = *(const bf16x8*)(ap + kt);
        #pragma unroll
        for (int n = 0; n < 6; ++n) {
            bf16x8 wf = *(const bf16x8*)(w_outT + (size_t)(n * 16 + lr) * U_ + kt + lk);
            acc[n] = MFMA(af, wf, acc[n]);
        }
    }
    const int l4 = (l >> 4) * 4;
    #pragma unroll
    for (int n = 0; n < 6; ++n) {
        const int col = n * 16 + lr;
        if (col < DIN_) {
            #pragma unroll
            for (int r = 0; r < 4; ++r) {
                int row = m0 + l4 + r;                  // = tstep*64 + b
                int tt = row >> 6, b = row & 63;
                out[((size_t)b * T_ + tt) * DIN_ + col] = acc[n][r] + b_out[col];
            }
        }
    }
}

extern "C" void kernel_launch(void* const* d_in, const int* in_sizes, int n_in,
                              void* d_out, int out_size, void* d_ws, size_t ws_size,
                              hipStream_t stream)
{
    const float* z      = (const float*)d_in[0];
    const float* w_init = (const float*)d_in[1];
    const float* b_init = (const float*)d_in[2];
    const float* k0     = (const float*)d_in[3];
    const float* rk0    = (const float*)d_in[4];
    const float* b0     = (const float*)d_in[5];
    const float* k1     = (const float*)d_in[6];
    const float* rk1    = (const float*)d_in[7];
    const float* b1     = (const float*)d_in[8];
    const float* k2     = (const float*)d_in[9];
    const float* rk2    = (const float*)d_in[10];
    const float* b2     = (const float*)d_in[11];
    const float* w_out  = (const float*)d_in[12];
    const float* b_out  = (const float*)d_in[13];
    float* out = (float*)d_out;
    (void)in_sizes; (void)n_in; (void)out_size; (void)ws_size;

    // workspace carve-up (256B aligned), total ~210 MB
    size_t off = 0;
    char* base = (char*)d_ws;
    auto alloc = [&](size_t bytes) { void* p = base + off; off += (bytes + 255) & ~(size_t)255; return p; };
    unsigned short* rk0P = (unsigned short*)alloc((size_t)U_ * G4_ * 2);
    unsigned short* rk1P = (unsigned short*)alloc((size_t)U_ * G4_ * 2);
    unsigned short* rk2P = (unsigned short*)alloc((size_t)U_ * G4_ * 2);
    unsigned short* k1P  = (unsigned short*)alloc((size_t)U_ * G4_ * 2);
    unsigned short* k2P  = (unsigned short*)alloc((size_t)U_ * G4_ * 2);
    unsigned short* wiT  = (unsigned short*)alloc((size_t)STLD * Z_ * 2);
    unsigned short* k0T  = (unsigned short*)alloc((size_t)G4_ * Z_ * 2);
    unsigned short* woT  = (unsigned short*)alloc((size_t)96 * U_ * 2);
    unsigned short* zb   = (unsigned short*)alloc((size_t)B_ * Z_ * 2);
    unsigned short* hb0[2], *hb1[2];
    for (int p = 0; p < 2; ++p) hb0[p] = (unsigned short*)alloc((size_t)B_ * U_ * 2);
    for (int p = 0; p < 2; ++p) hb1[p] = (unsigned short*)alloc((size_t)B_ * U_ * 2);
    unsigned short* h2hist = (unsigned short*)alloc((size_t)(T_ + 1) * B_ * U_ * 2);
    float* st   = (float*)alloc((size_t)B_ * STLD * 4);
    float* xk0  = (float*)alloc((size_t)B_ * G4_ * 4);
    float* zg1  = (float*)alloc((size_t)B_ * G4_ * 4);
    float* zg2  = (float*)alloc((size_t)B_ * G4_ * 4);
    float* cst0 = (float*)alloc((size_t)B_ * U_ * 4);
    float* cst1 = (float*)alloc((size_t)B_ * U_ * 4);
    float* cst2 = (float*)alloc((size_t)B_ * U_ * 4);

    // --- one-time conversions ---
    transpose_cvt_packed<<<dim3(G4_ / 32, U_ / 32), 256, 0, stream>>>(rk0, rk0P);
    transpose_cvt_packed<<<dim3(G4_ / 32, U_ / 32), 256, 0, stream>>>(rk1, rk1P);
    transpose_cvt_packed<<<dim3(G4_ / 32, U_ / 32), 256, 0, stream>>>(rk2, rk2P);
    transpose_cvt_packed<<<dim3(G4_ / 32, U_ / 32), 256, 0, stream>>>(k1, k1P);
    transpose_cvt_packed<<<dim3(G4_ / 32, U_ / 32), 256, 0, stream>>>(k2, k2P);
    transpose_cvt<<<dim3(STLD / 32, Z_ / 32), 256, 0, stream>>>(w_init, wiT, Z_, STLD, 0);
    transpose_cvt<<<dim3(G4_ / 32, Z_ / 32), 256, 0, stream>>>(k0, k0T, Z_, G4_, DIN_);
    wout_cvt<<<dim3(96 * U_ / 256), 256, 0, stream>>>(w_out, woT);
    cvt_z<<<dim3(B_ * Z_ / 256), 256, 0, stream>>>(z, zb);

    // --- setup: st = zb @ wiT^T + b_init ; xk0 = zb @ k0T^T + b0 ---
    gemm_plain<<<dim3(STLD / 64), 256, 0, stream>>>(zb, Z_, wiT, b_init, st, STLD);
    gemm_plain<<<dim3(G4_ / 64), 256, 0, stream>>>(zb, Z_, k0T, b0, xk0, G4_);
    hcinit<<<dim3(3 * B_ * U_ / 256), 256, 0, stream>>>(st, hb0[0], hb1[0], h2hist,
                                                        cst0, cst1, cst2);

    // --- pipelined time loop: 2 launches/step (X: kgate2(t-1)||rec0(t)||rec1(t); Y: rec2(t)||kgate1(t)) ---
    // t=0 prologue (no kgate2 yet)
    stepX0<<<dim3(U_ / 8, 2, 2), 256, 0, stream>>>(hb0[0], rk0P, xk0, cst0, hb0[1],
                                                   hb1[0], rk1P, zg1);
    stepY<<<dim3(U_ / 8, 2, 2), 256, 0, stream>>>(h2hist, rk2P, zg2,
                                                  hb0[1], k1P, zg1, b1, cst1, hb1[1]);
    for (int tstep = 1; tstep < T_; ++tstep) {
        const int p = tstep & 1;
        // X(t): kgate2(t-1) uses h1_new(t-1)=hb1[p], zg2; rec0(t) reads hb0[p]; rec1(t) reads hb1[p]
        stepX<<<dim3(U_ / 8, 2, 3), 256, 0, stream>>>(
            hb1[p], k2P, zg2, b2, cst2, h2hist + (size_t)tstep * B_ * U_,
            hb0[p], rk0P, xk0, cst0, hb0[p ^ 1],
            hb1[p], rk1P, zg1);
        // Y(t): rec2(t) reads h2hist slot t; kgate1(t) reads hb0[p^1], zg1 -> hb1[p^1]
        stepY<<<dim3(U_ / 8, 2, 2), 256, 0, stream>>>(
            h2hist + (size_t)tstep * B_ * U_, rk2P, zg2,
            hb0[p ^ 1], k1P, zg1, b1, cst1, hb1[p ^ 1]);
    }
    // epilogue: lone kgate2(31): h1_new(31)=hb1[(31&1)^1]=hb1[0]
    kgate<<<dim3(U_ / 8, 2), 256, 0, stream>>>(hb1[0], k2P, zg2, b2, cst2,
                                               h2hist + (size_t)T_ * B_ * U_);
    // --- all 32 output projections in one GEMM ---
    outproj_all<<<dim3(T_ * B_ / 64), 256, 0, stream>>>(h2hist + (size_t)B_ * U_, woT, b_out, out);
}

// Round 14
// 1489.195 us; speedup vs baseline: 2.0350x; 1.3022x over previous
//
#include <hip/hip_runtime.h>
#include <cstdint>

// Problem constants
#define B_   64
#define Z_   512
#define U_   2048
#define T_   32
#define DIN_ 90
#define G4_  8192      // 4*U
#define STLD 12288     // setup GEMM output row stride: h at +l*4096, c at +l*4096+2048

using bf16x8 = __attribute__((ext_vector_type(8))) short;   // 8 bf16 = 4 VGPRs
using f32x4  = __attribute__((ext_vector_type(4))) float;

#define MFMA(a, b, c) __builtin_amdgcn_mfma_f32_16x16x32_bf16((a), (b), (c), 0, 0, 0)

__device__ __forceinline__ unsigned short f2bf(float f) {
    unsigned int u = __float_as_uint(f);
    unsigned int r = (u + 0x7FFFu + ((u >> 16) & 1u)) >> 16;   // RNE
    return (unsigned short)r;
}
__device__ __forceinline__ float sigf(float x) { return 1.f / (1.f + expf(-x)); }

// async global->LDS, 16 B per lane; LDS dest is wave-uniform base + lane*16
__device__ __forceinline__ void gld16(const void* g, void* l) {
    __builtin_amdgcn_global_load_lds(
        (const __attribute__((address_space(1))) unsigned int*)g,
        (__attribute__((address_space(3))) unsigned int*)l, 16, 0, 0);
}

// ======== staged K=2048 GEMM core as macros (LDS at kernel scope; passing ========
// ======== __shared__ pointers through fn params ICEs clang — r11 lesson)  ========
// 512 threads = 8 waves. Block tile: 64 rows x 32 packed cols (W panel read ONCE
// per launch — r13's y-split read it twice). Wave (rq=wv&3, ch=wv>>2) does 16x16.
// KT=128; stage = A 16KB | W 8KB = 24KB; 3 stages = 72KB; counted vmcnt(3).
// T2 XOR swizzle via pre-swizzled global source. sg aliases stage buffer 2
// (last tile reads buffer 0; defensive barrier before fill).
// Requires in scope: stg, t, wv, l, prow0, rq, ch, lr.
#define GEMM_PROLOG()                                                        \
    size_t ag0, ag1, wg0; unsigned al0, al1, wl0;                            \
    {                                                                        \
        int kb0 = (l & 15) << 4;                                             \
        int r0 = wv * 4 + (l >> 4);                   /* A rows 0..31 */     \
        int sw0 = kb0 ^ ((r0 & 7) << 4);                                     \
        ag0 = (size_t)r0 * U_ + (sw0 >> 1);                                  \
        al0 = wv * 1024;                                                     \
        int r1 = 32 + r0;                             /* A rows 32..63 */    \
        int sw1 = kb0 ^ ((r1 & 7) << 4);                                     \
        ag1 = (size_t)r1 * U_ + (sw1 >> 1);                                  \
        al1 = 8192 + wv * 1024;                                              \
        int rw = r0;                                  /* W rows 0..31 */     \
        int sww = kb0 ^ ((rw & 7) << 4);                                     \
        wg0 = (size_t)(prow0 + rw) * U_ + (sww >> 1);                        \
        wl0 = 16384 + wv * 1024;                                             \
    }                                                                        \
    int aoff[4], woff[4];                                                    \
    {                                                                        \
        const int lkb = (l >> 4) << 4;                                       \
        _Pragma("unroll")                                                    \
        for (int ks = 0; ks < 4; ++ks) {                                     \
            int kb = ks * 64 + lkb;                                          \
            int ar = rq * 16 + lr, wr = ch * 16 + lr;                        \
            aoff[ks] = ar * 256 + (kb ^ ((ar & 7) << 4));                    \
            woff[ks] = 16384 + wr * 256 + (kb ^ ((wr & 7) << 4));            \
        }                                                                    \
    }

#define ISSUE(Ap, Wp, tt) do {                                               \
        const int k0_ = (tt) * 128;                                          \
        char* sb_ = stg + ((tt) % 3) * 24576;                                \
        gld16((Ap) + ag0 + k0_, sb_ + al0);                                  \
        gld16((Ap) + ag1 + k0_, sb_ + al1);                                  \
        gld16((Wp) + wg0 + k0_, sb_ + wl0);                                  \
    } while (0)

#define GEMM_LOOP(Ap, Wp)                                                    \
    ISSUE(Ap, Wp, 0);                                                        \
    ISSUE(Ap, Wp, 1);                                                        \
    for (int tt = 0; tt < 16; ++tt) {                                        \
        if (tt < 15) asm volatile("s_waitcnt vmcnt(3)" ::: "memory");        \
        else         asm volatile("s_waitcnt vmcnt(0)" ::: "memory");        \
        __builtin_amdgcn_s_barrier();                                        \
        if (tt + 2 < 16) ISSUE(Ap, Wp, tt + 2);                              \
        const char* sb = stg + (tt % 3) * 24576;                             \
        _Pragma("unroll")                                                    \
        for (int ks = 0; ks < 4; ++ks) {                                     \
            bf16x8 av = *(const bf16x8*)(sb + aoff[ks]);                     \
            bf16x8 wf = *(const bf16x8*)(sb + woff[ks]);                     \
            acc = MFMA(av, wf, acc);                                         \
        }                                                                    \
    }

// mode-1 epilogue: nontemporal store S tile (64 rows x 32 cols) to ZG
#define EPI_ZG(ZG) do {                                                      \
        const int l4_ = (l >> 4) << 2;                                       \
        _Pragma("unroll")                                                    \
        for (int r = 0; r < 4; ++r) {                                        \
            int row = rq * 16 + l4_ + r;                                     \
            int col = prow0 + ch * 16 + lr;                                  \
            __builtin_nontemporal_store(acc[r], &(ZG)[(size_t)row * G4_ + col]); \
        }                                                                    \
    } while (0)

// gate epilogues: fill sg (plain or +zg), then LSTM cell for 64 rows x 8 units
#define EPI_FILL_PLAIN() do {                                                \
        __syncthreads();   /* sg aliases stage buf 2 */                      \
        const int l4_ = (l >> 4) << 2;                                       \
        _Pragma("unroll")                                                    \
        for (int r = 0; r < 4; ++r)                                          \
            sg[rq * 16 + l4_ + r][ch * 16 + lr] = acc[r];                    \
    } while (0)

#define EPI_FILL_ZG(ZGIN) do {                                               \
        __syncthreads();   /* sg aliases stage buf 2 */                      \
        const int l4_ = (l >> 4) << 2;                                       \
        _Pragma("unroll")                                                    \
        for (int r = 0; r < 4; ++r) {                                        \
            int row = rq * 16 + l4_ + r;                                     \
            int col = prow0 + ch * 16 + lr;                                  \
            sg[row][ch * 16 + lr] =                                          \
                acc[r] + __builtin_nontemporal_load(&(ZGIN)[(size_t)row * G4_ + col]); \
        }                                                                    \
    } while (0)

// BASEEXPR may use b, u, gi. 512 threads cover 64 rows x 8 units exactly.
#define EPI_GATE(BASEEXPR, CST, HNEW) do {                                   \
        __syncthreads();                                                     \
        const int b = t >> 3, uu = t & 7;                                    \
        const int u = blockIdx.x * 8 + uu;                                   \
        float g[4];                                                          \
        _Pragma("unroll")                                                    \
        for (int gi = 0; gi < 4; ++gi)                                       \
            g[gi] = sg[b][gi * 8 + uu] + (BASEEXPR);                         \
        float* cp = (CST) + (size_t)b * U_ + u;                              \
        const float c_ = *cp;                                                \
        const float cn = sigf(g[1]) * c_ + sigf(g[0]) * tanhf(g[2]);         \
        const float hn = sigf(g[3]) * tanhf(cn);                             \
        *cp = cn;                                                            \
        (HNEW)[(size_t)b * U_ + u] = f2bf(hn);                               \
    } while (0)

#define STEP_COMMON()                                                        \
    __shared__ char stg[3 * 24576];                                          \
    auto sg = reinterpret_cast<float(*)[33]>(stg + 2 * 24576);               \
    const int t = threadIdx.x, wv = t >> 6, l = t & 63;                      \
    const int prow0 = blockIdx.x * 32;                                       \
    const int rq = wv & 3, ch = wv >> 2, lr = l & 15;

// ---------------- one-time weight prep ----------------

__global__ __launch_bounds__(256) void transpose_cvt(const float* __restrict__ W,
                                                     unsigned short* __restrict__ Wt,
                                                     int K, int N, int row_off)
{
    __shared__ float tile[32][33];
    const int nb = blockIdx.x * 32, kb = blockIdx.y * 32;
    const int tx = threadIdx.x & 31, ty = threadIdx.x >> 5;   // 32 x 8
    #pragma unroll
    for (int i = 0; i < 4; ++i)
        tile[ty + i * 8][tx] = W[(size_t)(row_off + kb + ty + i * 8) * N + nb + tx];
    __syncthreads();
    #pragma unroll
    for (int i = 0; i < 4; ++i)
        Wt[(size_t)(nb + ty + i * 8) * K + kb + tx] = f2bf(tile[tx][ty + i * 8]);
}

// Packed transpose: original col n = g*2048+u -> packed row (u>>3)*32 + g*8 + (u&7).
__global__ __launch_bounds__(256) void transpose_cvt_packed(const float* __restrict__ W,
                                                            unsigned short* __restrict__ Wt)
{
    __shared__ float tile[32][33];
    const int nb = blockIdx.x * 32, kb = blockIdx.y * 32;   // N=8192, K=2048
    const int tx = threadIdx.x & 31, ty = threadIdx.x >> 5;
    #pragma unroll
    for (int i = 0; i < 4; ++i)
        tile[ty + i * 8][tx] = W[(size_t)(kb + ty + i * 8) * G4_ + nb + tx];
    __syncthreads();
    #pragma unroll
    for (int i = 0; i < 4; ++i) {
        int n = nb + ty + i * 8;
        int g = n >> 11, u = n & 2047;
        int prow = ((u >> 3) << 5) + (g << 3) + (u & 7);
        Wt[(size_t)prow * U_ + kb + tx] = f2bf(tile[tx][ty + i * 8]);
    }
}

// w_outT[d][k] = bf16(w_out[k*90+d]) for d<90, else 0   (96 x 2048)
__global__ __launch_bounds__(256) void wout_cvt(const float* __restrict__ w_out,
                                                unsigned short* __restrict__ w_outT)
{
    int i = blockIdx.x * 256 + threadIdx.x;        // 96*2048
    int d = i >> 11, k = i & 2047;
    w_outT[i] = (d < DIN_) ? f2bf(w_out[(size_t)k * DIN_ + d]) : (unsigned short)0;
}

__global__ __launch_bounds__(256) void cvt_z(const float* __restrict__ z,
                                             unsigned short* __restrict__ zb)
{
    int i = blockIdx.x * 256 + threadIdx.x;        // 64*512
    zb[i] = f2bf(z[i]);
}

// initial h (bf16) and c (fp32) from the setup GEMM output st
__global__ __launch_bounds__(256) void hcinit(const float* __restrict__ st,
                                              unsigned short* __restrict__ h0,
                                              unsigned short* __restrict__ h1,
                                              unsigned short* __restrict__ h2s0,
                                              float* __restrict__ c0,
                                              float* __restrict__ c1,
                                              float* __restrict__ c2)
{
    int idx = blockIdx.x * 256 + threadIdx.x;      // 3*64*2048
    int u = idx & 2047, b = (idx >> 11) & 63, ly = idx >> 17;
    float hv = st[(size_t)b * STLD + ly * 4096 + u];
    float cv = st[(size_t)b * STLD + ly * 4096 + 2048 + u];
    unsigned short* h = (ly == 0) ? h0 : (ly == 1) ? h1 : h2s0;
    float* c = (ly == 0) ? c0 : (ly == 1) ? c1 : c2;
    h[(size_t)b * 2048 + u] = f2bf(hv);
    c[(size_t)b * 2048 + u] = cv;
}

// ---------------- setup GEMMs (K=512): out[64 x N] = A @ Wt^T + bias ----------------
__global__ __launch_bounds__(256) void gemm_plain(const unsigned short* __restrict__ A, int K,
                                                  const unsigned short* __restrict__ Wt,
                                                  const float* __restrict__ bias,
                                                  float* __restrict__ out, int ldo)
{
    const int t = threadIdx.x, wv = t >> 6, l = t & 63;
    const int wm = (wv >> 1) * 32, n0 = blockIdx.x * 64 + (wv & 1) * 32;
    const int lr = l & 15, lk = (l >> 4) * 8;
    f32x4 acc[2][2] = {};
    for (int kt = 0; kt < K; kt += 32) {
        bf16x8 a0 = *(const bf16x8*)(A + (size_t)(wm + lr) * K + kt + lk);
        bf16x8 a1 = *(const bf16x8*)(A + (size_t)(wm + 16 + lr) * K + kt + lk);
        bf16x8 w0 = *(const bf16x8*)(Wt + (size_t)(n0 + lr) * K + kt + lk);
        bf16x8 w1 = *(const bf16x8*)(Wt + (size_t)(n0 + 16 + lr) * K + kt + lk);
        acc[0][0] = MFMA(a0, w0, acc[0][0]);
        acc[0][1] = MFMA(a0, w1, acc[0][1]);
        acc[1][0] = MFMA(a1, w0, acc[1][0]);
        acc[1][1] = MFMA(a1, w1, acc[1][1]);
    }
    #pragma unroll
    for (int mi = 0; mi < 2; ++mi)
        #pragma unroll
        for (int ni = 0; ni < 2; ++ni)
            #pragma unroll
            for (int r = 0; r < 4; ++r) {
                int row = wm + mi * 16 + (l >> 4) * 4 + r;
                int col = n0 + ni * 16 + lr;
                out[(size_t)row * ldo + col] = acc[mi][ni][r] + bias[col];
            }
}

// ---------------- pipelined step kernels (512 threads, 64-row blocks) ----------------
// X0 (t=0 prologue): z=0 -> rec0(0); z=1 -> rec1(0)
__global__ __launch_bounds__(512) void stepX0(
    const unsigned short* __restrict__ h0old, const unsigned short* __restrict__ rk0P,
    const float* __restrict__ xk0, float* __restrict__ cst0,
    unsigned short* __restrict__ h0new,
    const unsigned short* __restrict__ h1old, const unsigned short* __restrict__ rk1P,
    float* __restrict__ zg1)
{
    STEP_COMMON();
    const int z = blockIdx.y;
    const unsigned short* A = (z == 0) ? h0old : h1old;
    const unsigned short* W = (z == 0) ? rk0P : rk1P;

    GEMM_PROLOG();
    f32x4 acc = {};
    GEMM_LOOP(A, W);

    if (z == 0) {
        EPI_FILL_PLAIN();
        EPI_GATE(xk0[(size_t)b * G4_ + gi * 2048 + u], cst0, h0new);
    } else {
        EPI_ZG(zg1);
    }
}

// X (t>=1): z=0 -> kgate2(t-1); z=1 -> rec0(t); z=2 -> rec1(t)
__global__ __launch_bounds__(512) void stepX(
    const unsigned short* __restrict__ h1prev, const unsigned short* __restrict__ k2P,
    const float* __restrict__ zg2in, const float* __restrict__ b2v,
    float* __restrict__ cst2, unsigned short* __restrict__ h2out,
    const unsigned short* __restrict__ h0old, const unsigned short* __restrict__ rk0P,
    const float* __restrict__ xk0, float* __restrict__ cst0,
    unsigned short* __restrict__ h0new,
    const unsigned short* __restrict__ h1old, const unsigned short* __restrict__ rk1P,
    float* __restrict__ zg1out)
{
    STEP_COMMON();
    const int z = blockIdx.y;
    const unsigned short* A = (z == 0) ? h1prev : (z == 1) ? h0old : h1old;
    const unsigned short* W = (z == 0) ? k2P : (z == 1) ? rk0P : rk1P;

    GEMM_PROLOG();
    f32x4 acc = {};
    GEMM_LOOP(A, W);

    if (z == 0) {
        EPI_FILL_ZG(zg2in);
        EPI_GATE(b2v[gi * 2048 + u], cst2, h2out);
    } else if (z == 1) {
        EPI_FILL_PLAIN();
        EPI_GATE(xk0[(size_t)b * G4_ + gi * 2048 + u], cst0, h0new);
    } else {
        EPI_ZG(zg1out);
    }
}

// Y: z=0 -> rec2(t); z=1 -> kgate1(t)
__global__ __launch_bounds__(512) void stepY(
    const unsigned short* __restrict__ h2cur, const unsigned short* __restrict__ rk2P,
    float* __restrict__ zg2out,
    const unsigned short* __restrict__ h0new, const unsigned short* __restrict__ k1P,
    const float* __restrict__ zg1in, const float* __restrict__ b1v,
    float* __restrict__ cst1, unsigned short* __restrict__ h1new)
{
    STEP_COMMON();
    const int z = blockIdx.y;
    const unsigned short* A = (z == 0) ? h2cur : h0new;
    const unsigned short* W = (z == 0) ? rk2P : k1P;

    GEMM_PROLOG();
    f32x4 acc = {};
    GEMM_LOOP(A, W);

    if (z == 0) {
        EPI_ZG(zg2out);
    } else {
        EPI_FILL_ZG(zg1in);
        EPI_GATE(b1v[gi * 2048 + u], cst1, h1new);
    }
}

// standalone kgate (epilogue: lone kgate2(31))
__global__ __launch_bounds__(512) void kgate(
    const unsigned short* __restrict__ xNew, const unsigned short* __restrict__ kP,
    const float* __restrict__ zgin, const float* __restrict__ bias,
    float* __restrict__ cst, unsigned short* __restrict__ hNew)
{
    STEP_COMMON();
    GEMM_PROLOG();
    f32x4 acc = {};
    GEMM_LOOP(xNew, kP);

    EPI_FILL_ZG(zgin);
    EPI_GATE(bias[gi * 2048 + u], cst, hNew);
}

// ---------------- batched output projection: ONE GEMM after the time loop ----------------
__global__ __launch_bounds__(256) void outproj_all(const unsigned short* __restrict__ h2h,
                                                   const unsigned short* __restrict__ w_outT,
                                                   const float* __restrict__ b_out,
                                                   float* __restrict__ out)
{
    const int t = threadIdx.x, wv = t >> 6, l = t & 63;
    const int m0 = blockIdx.x * 64 + wv * 16;
    const int lr = l & 15, lk = (l >> 4) * 8;
    const unsigned short* ap = h2h + (size_t)(m0 + lr) * U_ + lk;
    f32x4 acc[6] = {};
    for (int kt = 0; kt < U_; kt += 32) {
        bf16x8 af = *(const bf16x8*)(ap + kt);
        #pragma unroll
        for (int n = 0; n < 6; ++n) {
            bf16x8 wf = *(const bf16x8*)(w_outT + (size_t)(n * 16 + lr) * U_ + kt + lk);
            acc[n] = MFMA(af, wf, acc[n]);
        }
    }
    const int l4 = (l >> 4) * 4;
    #pragma unroll
    for (int n = 0; n < 6; ++n) {
        const int col = n * 16 + lr;
        if (col < DIN_) {
            #pragma unroll
            for (int r = 0; r < 4; ++r) {
                int row = m0 + l4 + r;                  // = tstep*64 + b
                int tt = row >> 6, b = row & 63;
                out[((size_t)b * T_ + tt) * DIN_ + col] = acc[n][r] + b_out[col];
            }
        }
    }
}

extern "C" void kernel_launch(void* const* d_in, const int* in_sizes, int n_in,
                              void* d_out, int out_size, void* d_ws, size_t ws_size,
                              hipStream_t stream)
{
    const float* z      = (const float*)d_in[0];
    const float* w_init = (const float*)d_in[1];
    const float* b_init = (const float*)d_in[2];
    const float* k0     = (const float*)d_in[3];
    const float* rk0    = (const float*)d_in[4];
    const float* b0     = (const float*)d_in[5];
    const float* k1     = (const float*)d_in[6];
    const float* rk1    = (const float*)d_in[7];
    const float* b1     = (const float*)d_in[8];
    const float* k2     = (const float*)d_in[9];
    const float* rk2    = (const float*)d_in[10];
    const float* b2     = (const float*)d_in[11];
    const float* w_out  = (const float*)d_in[12];
    const float* b_out  = (const float*)d_in[13];
    float* out = (float*)d_out;
    (void)in_sizes; (void)n_in; (void)out_size; (void)ws_size;

    // workspace carve-up (256B aligned), total ~210 MB
    size_t off = 0;
    char* base = (char*)d_ws;
    auto alloc = [&](size_t bytes) { void* p = base + off; off += (bytes + 255) & ~(size_t)255; return p; };
    unsigned short* rk0P = (unsigned short*)alloc((size_t)U_ * G4_ * 2);
    unsigned short* rk1P = (unsigned short*)alloc((size_t)U_ * G4_ * 2);
    unsigned short* rk2P = (unsigned short*)alloc((size_t)U_ * G4_ * 2);
    unsigned short* k1P  = (unsigned short*)alloc((size_t)U_ * G4_ * 2);
    unsigned short* k2P  = (unsigned short*)alloc((size_t)U_ * G4_ * 2);
    unsigned short* wiT  = (unsigned short*)alloc((size_t)STLD * Z_ * 2);
    unsigned short* k0T  = (unsigned short*)alloc((size_t)G4_ * Z_ * 2);
    unsigned short* woT  = (unsigned short*)alloc((size_t)96 * U_ * 2);
    unsigned short* zb   = (unsigned short*)alloc((size_t)B_ * Z_ * 2);
    unsigned short* hb0[2], *hb1[2];
    for (int p = 0; p < 2; ++p) hb0[p] = (unsigned short*)alloc((size_t)B_ * U_ * 2);
    for (int p = 0; p < 2; ++p) hb1[p] = (unsigned short*)alloc((size_t)B_ * U_ * 2);
    unsigned short* h2hist = (unsigned short*)alloc((size_t)(T_ + 1) * B_ * U_ * 2);
    float* st   = (float*)alloc((size_t)B_ * STLD * 4);
    float* xk0  = (float*)alloc((size_t)B_ * G4_ * 4);
    float* zg1  = (float*)alloc((size_t)B_ * G4_ * 4);
    float* zg2  = (float*)alloc((size_t)B_ * G4_ * 4);
    float* cst0 = (float*)alloc((size_t)B_ * U_ * 4);
    float* cst1 = (float*)alloc((size_t)B_ * U_ * 4);
    float* cst2 = (float*)alloc((size_t)B_ * U_ * 4);

    // --- one-time conversions ---
    transpose_cvt_packed<<<dim3(G4_ / 32, U_ / 32), 256, 0, stream>>>(rk0, rk0P);
    transpose_cvt_packed<<<dim3(G4_ / 32, U_ / 32), 256, 0, stream>>>(rk1, rk1P);
    transpose_cvt_packed<<<dim3(G4_ / 32, U_ / 32), 256, 0, stream>>>(rk2, rk2P);
    transpose_cvt_packed<<<dim3(G4_ / 32, U_ / 32), 256, 0, stream>>>(k1, k1P);
    transpose_cvt_packed<<<dim3(G4_ / 32, U_ / 32), 256, 0, stream>>>(k2, k2P);
    transpose_cvt<<<dim3(STLD / 32, Z_ / 32), 256, 0, stream>>>(w_init, wiT, Z_, STLD, 0);
    transpose_cvt<<<dim3(G4_ / 32, Z_ / 32), 256, 0, stream>>>(k0, k0T, Z_, G4_, DIN_);
    wout_cvt<<<dim3(96 * U_ / 256), 256, 0, stream>>>(w_out, woT);
    cvt_z<<<dim3(B_ * Z_ / 256), 256, 0, stream>>>(z, zb);

    // --- setup: st = zb @ wiT^T + b_init ; xk0 = zb @ k0T^T + b0 ---
    gemm_plain<<<dim3(STLD / 64), 256, 0, stream>>>(zb, Z_, wiT, b_init, st, STLD);
    gemm_plain<<<dim3(G4_ / 64), 256, 0, stream>>>(zb, Z_, k0T, b0, xk0, G4_);
    hcinit<<<dim3(3 * B_ * U_ / 256), 256, 0, stream>>>(st, hb0[0], hb1[0], h2hist,
                                                        cst0, cst1, cst2);

    // --- pipelined time loop: 2 launches/step; each W panel fetched once ---
    stepX0<<<dim3(U_ / 8, 2), 512, 0, stream>>>(hb0[0], rk0P, xk0, cst0, hb0[1],
                                                hb1[0], rk1P, zg1);
    stepY<<<dim3(U_ / 8, 2), 512, 0, stream>>>(h2hist, rk2P, zg2,
                                               hb0[1], k1P, zg1, b1, cst1, hb1[1]);
    for (int tstep = 1; tstep < T_; ++tstep) {
        const int p = tstep & 1;
        stepX<<<dim3(U_ / 8, 3), 512, 0, stream>>>(
            hb1[p], k2P, zg2, b2, cst2, h2hist + (size_t)tstep * B_ * U_,
            hb0[p], rk0P, xk0, cst0, hb0[p ^ 1],
            hb1[p], rk1P, zg1);
        stepY<<<dim3(U_ / 8, 2), 512, 0, stream>>>(
            h2hist + (size_t)tstep * B_ * U_, rk2P, zg2,
            hb0[p ^ 1], k1P, zg1, b1, cst1, hb1[p ^ 1]);
    }
    // epilogue: lone kgate2(31): h1_new(31)=hb1[0]
    kgate<<<dim3(U_ / 8), 512, 0, stream>>>(hb1[0], k2P, zg2, b2, cst2,
                                            h2hist + (size_t)T_ * B_ * U_);
    // --- all 32 output projections in one GEMM ---
    outproj_all<<<dim3(T_ * B_ / 64), 256, 0, stream>>>(h2hist + (size_t)B_ * U_, woT, b_out, out);
}